// Round 25
// baseline (24.755 us; speedup 1.0000x reference)
//
#include <hip/hip_runtime.h>

#define IMG   512
#define NCLS  256
#define DIM   1024
#define HPW   32
#define TPB   8            // tokens per block (MFMA rows 8..15 zero); 256 blocks = full chip
#define NT    1024         // 16 waves; wave owns 64 dims
#define MAGIC 0x5EEDC0DEu

typedef short bf16x8 __attribute__((ext_vector_type(8)));
typedef float f32x4  __attribute__((ext_vector_type(4)));

__device__ inline ushort bf16rne(float v) {
    unsigned u = __float_as_uint(v);
    return (ushort)((u + 0x7fffu + ((u >> 16) & 1u)) >> 16);
}

// R23 skeleton (best: 18.75 us). SINGLE change: TPB 16->8, 256 blocks (full chip).
// Block bid packs dtile = bid>>2, class-quarter q = bid&3 (64 classes = 2 KB slice).
//   Tt2[dtile*4096 + ks*512 + g*128 + c*8 + j] = bf16(table[ks*32+g*8+j][dtile*16+c])
__global__ __launch_bounds__(NT)
void fused_one(const int* __restrict__ smap, const float* __restrict__ table,
               const float* __restrict__ gamma, const float* __restrict__ beta,
               float* __restrict__ out, ushort* __restrict__ Tt2,
               unsigned* __restrict__ flags)
{
    __shared__ unsigned cnt[TPB * NCLS];      // 8 KB
    __shared__ ushort   pk[1024];             // 2 KB pack staging (this block's slice)
    __shared__ ushort   cntb[16][264];        // rows 8..15 stay zero; stride 528 B
    __shared__ float    red[16][2][4][2];     // [wave][g][i][{s,s2}]

    const int t    = threadIdx.x;
    const int lane = t & 63;
    const int w    = t >> 6;
    const int c    = lane & 15;
    const int g    = lane >> 4;

    const int bid  = blockIdx.x;
    const int tok0 = bid * TPB;
    const int b    = tok0 >> 10;
    const int ph   = (tok0 >> 5) & 31;
    const int pw0  = tok0 & 31;               // 0, 8, 16, 24

    const int dtile = bid >> 2;               // 0..63
    const int q     = bid & 3;                // class quarter (64 classes)

    // ---- 1) pack-load: 64 cls x 16 dims -> LDS scatter (fragment order) ----
    if (t < 256) {
        const int cls  = q * 64 + (t >> 2);
        const int quad = t & 3;
        const float4 v = *reinterpret_cast<const float4*>(
            table + (size_t)cls * DIM + dtile * 16 + quad * 4);
        const int ks = cls >> 5, gg = (cls >> 3) & 3, j = cls & 7;
        ushort* dst = pk + (ks & 1) * 512 + gg * 128 + j;   // + c*8
        dst[(quad * 4 + 0) * 8] = bf16rne(v.x);
        dst[(quad * 4 + 1) * 8] = bf16rne(v.y);
        dst[(quad * 4 + 2) * 8] = bf16rne(v.z);
        dst[(quad * 4 + 3) * 8] = bf16rne(v.w);
    }
    // ---- 2) zero hist + cntb (rows 8..15 must be zero for MFMA) ----
    #pragma unroll
    for (int i = t; i < TPB * NCLS; i += NT) cnt[i] = 0u;
    #pragma unroll
    for (int i = t; i < 16 * 264; i += NT) (&cntb[0][0])[i] = 0;
    __syncthreads();

    // ---- 3) pack copy-out: system-scope atomic dwords (bypass L2 -> coherent) ----
    if (t < 512) {
        const unsigned val = (unsigned)pk[t * 2] | ((unsigned)pk[t * 2 + 1] << 16);
        __hip_atomic_store((unsigned*)Tt2 + (size_t)dtile * 2048 + q * 512 + t, val,
                           __ATOMIC_RELAXED, __HIP_MEMORY_SCOPE_SYSTEM);
    }
    __syncthreads();                          // drains every wave's stores (vmcnt 0)

    // ---- 4) publish pack completion (system-scope release) ----
    if (t == 0)
        __hip_atomic_store(&flags[bid], MAGIC, __ATOMIC_RELEASE, __HIP_MEMORY_SCOPE_SYSTEM);

    // ---- 5) histogram: 8 patches = 16 rows x 128 cols, int2 per thread ----
    {
        const int p   = t * 2;
        const int row = p >> 7;               // 0..15
        const int col = p & 127;
        const int2 qv = *reinterpret_cast<const int2*>(
            smap + ((size_t)b * IMG + (size_t)(ph * 16 + row)) * IMG + pw0 * 16 + col);
        unsigned* hp = &cnt[(col >> 4) * NCLS];
        atomicAdd(&hp[min(max(qv.x, 0), NCLS - 1)], 1u);
        atomicAdd(&hp[min(max(qv.y, 0), NCLS - 1)], 1u);
    }
    __syncthreads();

    // ---- 6) counts -> bf16(count/256), exact ----
    #pragma unroll
    for (int i = t; i < TPB * NCLS; i += NT)
        cntb[i >> 8][i & 255] = (ushort)(__float_as_uint((float)cnt[i] * (1.f / 256.f)) >> 16);

    // ---- 7) gate: RELAXED polls (no cache-inv storm), then ONE acquire ----
    if (t < 256) {
        while (__hip_atomic_load(&flags[t], __ATOMIC_RELAXED,
                                 __HIP_MEMORY_SCOPE_SYSTEM) != MAGIC) {}
    }
    __syncthreads();
    if (t == 0) {
        unsigned x = __hip_atomic_load(&flags[0], __ATOMIC_ACQUIRE,
                                       __HIP_MEMORY_SCOPE_SYSTEM);
        asm volatile("" :: "v"(x));           // keep the acquire load live
    }
    __syncthreads();

    // ---- 8) MFMA K-loop (verbatim R23) ----
    f32x4 acc[4];
    #pragma unroll
    for (int i = 0; i < 4; ++i) acc[i] = (f32x4){0.f, 0.f, 0.f, 0.f};

    const ushort* bt = Tt2 + (size_t)(w * 4) * 4096 + (size_t)lane * 8;
    #pragma unroll 2
    for (int ks = 0; ks < 8; ++ks) {
        const bf16x8 a = *reinterpret_cast<const bf16x8*>(&cntb[c][ks * 32 + g * 8]);
        bf16x8 bfv[4];
        #pragma unroll
        for (int nf = 0; nf < 4; ++nf)
            bfv[nf] = *reinterpret_cast<const bf16x8*>(bt + (size_t)nf * 4096 + ks * 512);
        #pragma unroll
        for (int nf = 0; nf < 4; ++nf)
            acc[nf] = __builtin_amdgcn_mfma_f32_16x16x32_bf16(a, bfv[nf], acc[nf], 0, 0, 0);
    }

    // ---- 9) pos-embed + LN partials (verbatim R23; valid rows r = g*4+i, g<2) ----
    const int quad   = w >> 2;
    const int cosSel = quad & 1;
    float ls[4]  = {0, 0, 0, 0};
    float ls2[4] = {0, 0, 0, 0};

    #pragma unroll
    for (int nf = 0; nf < 4; ++nf) {
        const int dlow = (w & 3) * 64 + nf * 16 + c;
        const float omega = exp2f((float)dlow * (-13.287712379549449f / 256.f));
        if (quad < 2) {
            float sv, cv; __sincosf((float)ph * omega, &sv, &cv);
            const float v = cosSel ? cv : sv;
            #pragma unroll
            for (int i = 0; i < 4; ++i) acc[nf][i] += v;
        } else {
            #pragma unroll
            for (int i = 0; i < 4; ++i) {
                float sv, cv; __sincosf((float)(pw0 + g * 4 + i) * omega, &sv, &cv);
                acc[nf][i] += cosSel ? cv : sv;
            }
        }
        #pragma unroll
        for (int i = 0; i < 4; ++i) { ls[i] += acc[nf][i]; ls2[i] += acc[nf][i] * acc[nf][i]; }
    }

    #pragma unroll
    for (int off = 1; off < 16; off <<= 1) {
        #pragma unroll
        for (int i = 0; i < 4; ++i) {
            ls[i]  += __shfl_xor(ls[i],  off, 64);
            ls2[i] += __shfl_xor(ls2[i], off, 64);
        }
    }
    if (c == 0 && g < 2) {
        #pragma unroll
        for (int i = 0; i < 4; ++i) { red[w][g][i][0] = ls[i]; red[w][g][i][1] = ls2[i]; }
    }
    __syncthreads();

    // ---- 10) finalize LN + store (valid rows r = g*4+i, g<2) ----
    if (g < 2) {
        float mu[4], rs[4];
        #pragma unroll
        for (int i = 0; i < 4; ++i) {
            float S = 0.f, S2 = 0.f;
            #pragma unroll
            for (int ww = 0; ww < 16; ++ww) { S += red[ww][g][i][0]; S2 += red[ww][g][i][1]; }
            mu[i] = S * (1.f / DIM);
            rs[i] = rsqrtf(S2 * (1.f / DIM) - mu[i] * mu[i] + 1e-5f);
        }
        #pragma unroll
        for (int nf = 0; nf < 4; ++nf) {
            const int d = w * 64 + nf * 16 + c;
            const float gv = gamma[d], bv = beta[d];
            #pragma unroll
            for (int i = 0; i < 4; ++i) {
                const int r = g * 4 + i;
                out[(size_t)(tok0 + r) * DIM + d] = (acc[nf][i] - mu[i]) * rs[i] * gv + bv;
            }
        }
    }
}

extern "C" void kernel_launch(void* const* d_in, const int* in_sizes, int n_in,
                              void* d_out, int out_size, void* d_ws, size_t ws_size,
                              hipStream_t stream) {
    const int*   smap  = (const int*)d_in[0];
    const float* table = (const float*)d_in[1];
    const float* gamma = (const float*)d_in[2];
    const float* beta  = (const float*)d_in[3];
    float*       out   = (float*)d_out;

    const int batches = in_sizes[0] / (IMG * IMG);       // = 2
    const int tokens  = batches * HPW * HPW;             // 2048
    const int nblk    = tokens / TPB;                    // 256 (pack mapping assumes this)

    ushort*   Tt2   = (ushort*)d_ws;                     // 512 KB packed table
    unsigned* flags = (unsigned*)(Tt2 + (size_t)64 * 4096);

    fused_one<<<nblk, NT, 0, stream>>>(smap, table, gamma, beta, out, Tt2, flags);
}

// Round 26
// 23.491 us; speedup vs baseline: 1.0538x; 1.0538x over previous
//
#include <hip/hip_runtime.h>

#define IMG   512
#define NCLS  256
#define DIM   1024
#define HPW   32
#define NT    1024         // 16 waves
#define MAGIC 0x5EEDC0DEu

typedef short bf16x8 __attribute__((ext_vector_type(8)));
typedef float f32x4  __attribute__((ext_vector_type(4)));

__device__ inline ushort bf16rne(float v) {
    unsigned u = __float_as_uint(v);
    return (ushort)((u + 0x7fffu + ((u >> 16) & 1u)) >> 16);
}

// Single launch, 256 blocks x 1024 thr.  Block = (grp = bid>>2, dq = bid&3):
// 32 tokens (one patch-row) x 256 dims.  B-slice = 128 KB/block (32 MB aggregate,
// half of the full-D design), all 256 CUs busy, pre-LN stays in registers.
// Pack role (independent indexing): dtile = bid>>2, class-quarter = bid&3 (R25's
// verified slice).  Gate pattern everywhere: system-scope stores + release flag +
// RELAXED polls + ONE acquire (R23's proven, storm-free handshake).
//   Tt2[dtile*4096 + ks*512 + g*128 + c*8 + j] = bf16(table[ks*32+g*8+j][dtile*16+c])
__global__ __launch_bounds__(NT)
void fused_one(const int* __restrict__ smap, const float* __restrict__ table,
               const float* __restrict__ gamma, const float* __restrict__ beta,
               float* __restrict__ out, ushort* __restrict__ Tt2,
               float* __restrict__ pstats, unsigned* __restrict__ flags,
               unsigned* __restrict__ flags2)
{
    __shared__ unsigned cnt[32 * NCLS];       // 32 KB hist
    __shared__ ushort   pk[1024];             // 2 KB pack staging
    __shared__ ushort   cntb[32][264];        // 16.5 KB A (32 tok x 256 cls, padded)
    __shared__ float    red[16][2][4][4][2];  // 4 KB [wave][mf][g][i][{s,s2}]
    __shared__ float    sstage[4][32][2];     // 1 KB sibling partials
    __shared__ float    mu_s[32], rs_s[32];

    const int t    = threadIdx.x;
    const int lane = t & 63;
    const int w    = t >> 6;                  // wave owns dims dq*256 + w*16 .. +16
    const int c    = lane & 15;
    const int g    = lane >> 4;

    const int bid  = blockIdx.x;
    const int grp  = bid >> 2;                // 0..63 token group (one patch-row)
    const int dq   = bid & 3;                 // dim quarter == sincos quadrant
    const int tok0 = grp * 32;
    const int b    = grp >> 5;
    const int ph   = grp & 31;

    const int dtile = bid >> 2;               // pack role: 0..63
    const int q     = bid & 3;                // pack role: class quarter

    // ---- 1) pack-load (t<256, R25 verified)  ||  zero hist (t>=256) ----
    if (t < 256) {
        const int cls  = q * 64 + (t >> 2);
        const int quad = t & 3;
        const float4 v = *reinterpret_cast<const float4*>(
            table + (size_t)cls * DIM + dtile * 16 + quad * 4);
        const int ks = cls >> 5, gg = (cls >> 3) & 3, j = cls & 7;
        ushort* dst = pk + (ks & 1) * 512 + gg * 128 + j;   // + c*8
        dst[(quad * 4 + 0) * 8] = bf16rne(v.x);
        dst[(quad * 4 + 1) * 8] = bf16rne(v.y);
        dst[(quad * 4 + 2) * 8] = bf16rne(v.z);
        dst[(quad * 4 + 3) * 8] = bf16rne(v.w);
    } else {
        for (int i = t - 256; i < 32 * NCLS; i += 768) cnt[i] = 0u;
    }
    __syncthreads();

    // ---- 2) pack copy-out: system-scope dwords (bypass L2 -> coherent) ----
    if (t < 512) {
        const unsigned val = (unsigned)pk[t * 2] | ((unsigned)pk[t * 2 + 1] << 16);
        __hip_atomic_store((unsigned*)Tt2 + (size_t)dtile * 2048 + q * 512 + t, val,
                           __ATOMIC_RELAXED, __HIP_MEMORY_SCOPE_SYSTEM);
    }
    __syncthreads();                          // drains all stores (vmcnt 0)

    // ---- 3) publish pack flag ASAP ----
    if (t == 0)
        __hip_atomic_store(&flags[bid], MAGIC, __ATOMIC_RELEASE, __HIP_MEMORY_SCOPE_SYSTEM);

    // ---- 4) histogram: one patch-row = 16 rows x 512 cols, 8 px/thread ----
    {
        const int row  = t >> 6;              // 0..15
        const int col0 = (t & 63) * 8;        // 0..504, stays within one patch
        const int* bp = smap + ((size_t)b * IMG + (size_t)(ph * 16 + row)) * IMG + col0;
        const int4 q0 = *reinterpret_cast<const int4*>(bp);
        const int4 q1 = *reinterpret_cast<const int4*>(bp + 4);
        unsigned* hp = &cnt[(col0 >> 4) * NCLS];
        atomicAdd(&hp[min(max(q0.x, 0), NCLS - 1)], 1u);
        atomicAdd(&hp[min(max(q0.y, 0), NCLS - 1)], 1u);
        atomicAdd(&hp[min(max(q0.z, 0), NCLS - 1)], 1u);
        atomicAdd(&hp[min(max(q0.w, 0), NCLS - 1)], 1u);
        atomicAdd(&hp[min(max(q1.x, 0), NCLS - 1)], 1u);
        atomicAdd(&hp[min(max(q1.y, 0), NCLS - 1)], 1u);
        atomicAdd(&hp[min(max(q1.z, 0), NCLS - 1)], 1u);
        atomicAdd(&hp[min(max(q1.w, 0), NCLS - 1)], 1u);
    }
    __syncthreads();

    // ---- 5) counts -> bf16(count/256), exact ----
    for (int i = t; i < 32 * NCLS; i += NT)
        cntb[i >> 8][i & 255] = (ushort)(__float_as_uint((float)cnt[i] * (1.f / 256.f)) >> 16);

    // ---- 6) gate 1: this block needs dtiles [dq*16, dq*16+16) = flags [dq*64, dq*64+64) ----
    if (t < 64) {
        while (__hip_atomic_load(&flags[dq * 64 + t], __ATOMIC_RELAXED,
                                 __HIP_MEMORY_SCOPE_SYSTEM) != MAGIC) {}
    }
    __syncthreads();
    if (t == 0) {
        unsigned x = __hip_atomic_load(&flags[dq * 64], __ATOMIC_ACQUIRE,
                                       __HIP_MEMORY_SCOPE_SYSTEM);
        asm volatile("" :: "v"(x));
    }
    __syncthreads();

    // ---- 7) MFMA: 2 M-tiles x 1 dtile/wave; 8 B-frags up front (R19 verified) ----
    f32x4 acc0 = (f32x4){0.f, 0.f, 0.f, 0.f};
    f32x4 acc1 = (f32x4){0.f, 0.f, 0.f, 0.f};
    const ushort* bt = Tt2 + (size_t)(dq * 16 + w) * 4096 + (size_t)lane * 8;
    bf16x8 bfv[8];
    #pragma unroll
    for (int ks = 0; ks < 8; ++ks)
        bfv[ks] = *reinterpret_cast<const bf16x8*>(bt + ks * 512);
    #pragma unroll
    for (int ks = 0; ks < 8; ++ks) {
        const bf16x8 a0 = *reinterpret_cast<const bf16x8*>(&cntb[c][ks * 32 + g * 8]);
        const bf16x8 a1 = *reinterpret_cast<const bf16x8*>(&cntb[16 + c][ks * 32 + g * 8]);
        acc0 = __builtin_amdgcn_mfma_f32_16x16x32_bf16(a0, bfv[ks], acc0, 0, 0, 0);
        acc1 = __builtin_amdgcn_mfma_f32_16x16x32_bf16(a1, bfv[ks], acc1, 0, 0, 0);
    }

    // ---- 8) pos-embed (R17 verified).  d = dq*256 + w*16 + c; pw = token ----
    {
        const float omega = exp2f((float)(w * 16 + c) * (-13.287712379549449f / 256.f));
        if (dq < 2) {
            float sv, cv; __sincosf((float)ph * omega, &sv, &cv);
            const float v = (dq & 1) ? cv : sv;
            #pragma unroll
            for (int i = 0; i < 4; ++i) { acc0[i] += v; acc1[i] += v; }
        } else {
            #pragma unroll
            for (int i = 0; i < 4; ++i) {
                float sv, cv;
                __sincosf((float)(g * 4 + i) * omega, &sv, &cv);
                acc0[i] += (dq & 1) ? cv : sv;
                __sincosf((float)(16 + g * 4 + i) * omega, &sv, &cv);
                acc1[i] += (dq & 1) ? cv : sv;
            }
        }
    }

    // ---- 9) LN partials over this block's 256 dims (R17 verified) ----
    float ls0[4], ls20[4], ls1[4], ls21[4];
    #pragma unroll
    for (int i = 0; i < 4; ++i) {
        ls0[i] = acc0[i]; ls20[i] = acc0[i] * acc0[i];
        ls1[i] = acc1[i]; ls21[i] = acc1[i] * acc1[i];
    }
    #pragma unroll
    for (int off = 1; off < 16; off <<= 1) {
        #pragma unroll
        for (int i = 0; i < 4; ++i) {
            ls0[i]  += __shfl_xor(ls0[i],  off, 64);
            ls20[i] += __shfl_xor(ls20[i], off, 64);
            ls1[i]  += __shfl_xor(ls1[i],  off, 64);
            ls21[i] += __shfl_xor(ls21[i], off, 64);
        }
    }
    if (c == 0) {
        #pragma unroll
        for (int i = 0; i < 4; ++i) {
            red[w][0][g][i][0] = ls0[i]; red[w][0][g][i][1] = ls20[i];
            red[w][1][g][i][0] = ls1[i]; red[w][1][g][i][1] = ls21[i];
        }
    }
    __syncthreads();

    // ---- 10) publish partial stats (system scope) + release flag2 ----
    if (t < 64) {
        const int token = t >> 1, which = t & 1;
        const int mf = token >> 4, gg = (token >> 2) & 3, ii = token & 3;
        float S = 0.f;
        #pragma unroll
        for (int ww = 0; ww < 16; ++ww) S += red[ww][mf][gg][ii][which];
        __hip_atomic_store(&pstats[(size_t)bid * 64 + token * 2 + which], S,
                           __ATOMIC_RELAXED, __HIP_MEMORY_SCOPE_SYSTEM);
    }
    __syncthreads();                          // drain pstats stores
    if (t == 0)
        __hip_atomic_store(&flags2[bid], MAGIC, __ATOMIC_RELEASE, __HIP_MEMORY_SCOPE_SYSTEM);

    // ---- 11) gate 2: 4 sibling flags, relaxed polls + one acquire ----
    if (t < 4) {
        while (__hip_atomic_load(&flags2[grp * 4 + t], __ATOMIC_RELAXED,
                                 __HIP_MEMORY_SCOPE_SYSTEM) != MAGIC) {}
    }
    __syncthreads();
    if (t == 0) {
        unsigned x = __hip_atomic_load(&flags2[grp * 4], __ATOMIC_ACQUIRE,
                                       __HIP_MEMORY_SCOPE_SYSTEM);
        asm volatile("" :: "v"(x));
    }
    __syncthreads();

    // ---- 12) combine sibling stats (R17 verified) ----
    if (t < 256) {
        const int dq2 = t >> 6, token = (t & 63) >> 1, which = t & 1;
        sstage[dq2][token][which] =
            pstats[(size_t)(grp * 4 + dq2) * 64 + token * 2 + which];
    }
    __syncthreads();
    if (t < 32) {
        float S = 0.f, S2 = 0.f;
        #pragma unroll
        for (int qq = 0; qq < 4; ++qq) { S += sstage[qq][t][0]; S2 += sstage[qq][t][1]; }
        const float mu = S * (1.f / DIM);
        mu_s[t] = mu;
        rs_s[t] = rsqrtf(S2 * (1.f / DIM) - mu * mu + 1e-5f);
    }
    __syncthreads();

    // ---- 13) normalize + store (R17 verified) ----
    {
        const int d = dq * 256 + w * 16 + c;
        const float gv = gamma[d], bv = beta[d];
        #pragma unroll
        for (int i = 0; i < 4; ++i) {
            const int r0 = g * 4 + i;
            out[(size_t)(tok0 + r0) * DIM + d]      = (acc0[i] - mu_s[r0])      * rs_s[r0]      * gv + bv;
            out[(size_t)(tok0 + 16 + r0) * DIM + d] = (acc1[i] - mu_s[16 + r0]) * rs_s[16 + r0] * gv + bv;
        }
    }
}

extern "C" void kernel_launch(void* const* d_in, const int* in_sizes, int n_in,
                              void* d_out, int out_size, void* d_ws, size_t ws_size,
                              hipStream_t stream) {
    const int*   smap  = (const int*)d_in[0];
    const float* table = (const float*)d_in[1];
    const float* gamma = (const float*)d_in[2];
    const float* beta  = (const float*)d_in[3];
    float*       out   = (float*)d_out;

    const int batches = in_sizes[0] / (IMG * IMG);       // = 2
    const int tokens  = batches * HPW * HPW;             // 2048
    const int nblk    = (tokens / 32) * 4;               // 256 (mappings assume this)

    ushort*   Tt2    = (ushort*)d_ws;                              // 512 KB
    float*    pstats = (float*)(Tt2 + (size_t)64 * 4096);          // 64 KB
    unsigned* flags  = (unsigned*)(pstats + (size_t)256 * 64);     // 1 KB
    unsigned* flags2 = flags + 256;                                // 1 KB

    fused_one<<<nblk, NT, 0, stream>>>(smap, table, gamma, beta, out,
                                       Tt2, pstats, flags, flags2);
}